// Round 1
// baseline (160.893 us; speedup 1.0000x reference)
//
#include <hip/hip_runtime.h>
#include <stdint.h>

// Problem constants (fixed shapes from reference)
#define M_ROWS 6272   // 32*196
#define K_DIM  768
#define N_DIM  3072
#define BM 128
#define BN 128
#define BK 32
#define NITER (K_DIM / BK)   // 24
#define WCOMP (768 * 192)    // f32 elems per weight component

typedef unsigned short u16;
typedef __attribute__((ext_vector_type(8))) __bf16 bf16x8;
typedef __attribute__((ext_vector_type(4))) float f32x4;

// LDS-only barrier: drains lgkmcnt (ds ops) but deliberately NOT vmcnt, so
// prefetched global loads stay in flight across the barrier. HIP's
// __syncthreads() always emits s_waitcnt vmcnt(0) before s_barrier, which
// welds global-load latency to every K-iteration.
__device__ __forceinline__ void lds_barrier() {
    asm volatile("s_waitcnt lgkmcnt(0)\n\ts_barrier" ::: "memory");
}

// 8x f32 -> 8x bf16 (RNE, hardware cvt; bit-identical to the old manual
// round-to-nearest-even pack for finite values, so numerics are unchanged).
__device__ __forceinline__ bf16x8 cvt8(float4 a, float4 b) {
    bf16x8 r;
    r[0] = (__bf16)a.x; r[1] = (__bf16)a.y; r[2] = (__bf16)a.z; r[3] = (__bf16)a.w;
    r[4] = (__bf16)b.x; r[5] = (__bf16)b.y; r[6] = (__bf16)b.z; r[7] = (__bf16)b.w;
    return r;
}

// Fully fused: C[m,n] = sum_k x[m,k] * Wexp[n,k] + bias[n], with Wexp the
// block-circulant expansion of weight_components read DIRECTLY from the f32
// originals during LDS staging (no prep kernel, no workspace).
//
// Key fact: BN=128 divides 768, so a col-tile lies inside one kblk =>
// component index i = (kblk - g/6) & 3 is block-uniform (scalar). Per K-tile g
// the B source offset is  i*WCOMP + (g - (g/6)*6)*32  floats, added to the
// per-thread row base  o*192 + s*8.
//
// Pipeline unchanged from the verified kernel: per iter each thread holds the
// NEXT tile's chunks in VGPRs (loaded one full iteration earlier, now as f32),
// converts + ds_writes them into the alternate LDS buffer after the MFMA
// phase, then issues loads for tile it+2. Barriers are lgkm-only so those
// loads ride across iterations.
//
// LDS XOR swizzle (verified, conflicts=0): 16B chunk for (row r, k-slot s)
// lives at slot s ^ ((r>>1)&3); applied on the GLOBAL source k-offset during
// staging, mirrored on the ds_read side.
__global__ __launch_bounds__(256) void gemm_fused(
    const float* __restrict__ x,     // [M_ROWS, K_DIM] f32
    const float* __restrict__ w,     // [4, 768, 192] f32 weight components
    const float* __restrict__ bias,  // [N_DIM] f32
    float* __restrict__ C)           // [M_ROWS, N_DIM] f32
{
    __shared__ __align__(16) u16 As[2][BM * BK];   // 2 x 8 KB
    __shared__ __align__(16) u16 Bs[2][BN * BK];   // 2 x 8 KB

    const int tid    = threadIdx.x;
    const int wave   = tid >> 6;
    const int lane   = tid & 63;
    const int lane16 = lane & 15;
    const int quad   = lane >> 4;
    const int wr     = wave >> 1;   // wave row (0..1) -> 64 rows each
    const int wc     = wave & 1;    // wave col (0..1) -> 64 cols each

    const int rowBase = blockIdx.y * BM;
    const int colBase = blockIdx.x * BN;
    const int kblk    = colBase / 768;        // block-uniform
    const int obase   = colBase - kblk * 768; // block-uniform

    // staging: chunk c in [0,512): row = c>>2, lds slot = c&3,
    // global k-slot = (c&3) ^ ((row>>1)&3). 16B (bf16) per chunk, read as 32B f32.
    const int c0 = tid;
    const int c1 = tid + 256;
    const int r0 = c0 >> 2, s0 = (c0 & 3) ^ ((r0 >> 1) & 3);
    const int r1 = c1 >> 2, s1 = (c1 & 3) ^ ((r1 >> 1) & 3);

    const float* Ap0 = x + (size_t)(rowBase + r0) * K_DIM + s0 * 8;
    const float* Ap1 = x + (size_t)(rowBase + r1) * K_DIM + s1 * 8;
    const float* Bp0 = w + (size_t)(obase + r0) * 192 + s0 * 8;
    const float* Bp1 = w + (size_t)(obase + r1) * 192 + s1 * 8;

    // circulant offset for K-tile g (block-uniform scalar math)
    auto wofs = [&](int g) -> int {
        int jg = g / 6;                 // 0..3
        int ig = (kblk - jg) & 3;       // component index
        return ig * WCOMP + (g - jg * 6) * 32;
    };

    float4 a00, a01, a10, a11, b00, b01, b10, b11;   // next tile, f32

#define LOADTILE(g) do {                                        \
        const float4* ap0 = (const float4*)(Ap0 + (g) * BK);    \
        const float4* ap1 = (const float4*)(Ap1 + (g) * BK);    \
        const int wo = wofs(g);                                 \
        const float4* bp0 = (const float4*)(Bp0 + wo);          \
        const float4* bp1 = (const float4*)(Bp1 + wo);          \
        a00 = ap0[0]; a01 = ap0[1];                             \
        a10 = ap1[0]; a11 = ap1[1];                             \
        b00 = bp0[0]; b01 = bp0[1];                             \
        b10 = bp1[0]; b11 = bp1[1];                             \
    } while (0)

#define STORETILE(buf) do {                                     \
        *(bf16x8*)&As[buf][c0 * 8] = cvt8(a00, a01);            \
        *(bf16x8*)&As[buf][c1 * 8] = cvt8(a10, a11);            \
        *(bf16x8*)&Bs[buf][c0 * 8] = cvt8(b00, b01);            \
        *(bf16x8*)&Bs[buf][c1 * 8] = cvt8(b10, b11);            \
    } while (0)

    // read-side swizzle
    const int swz  = (lane16 >> 1) & 3;
    const int slot = (quad ^ swz) * 8;
    int aoff[4], boff[4];
#pragma unroll
    for (int i = 0; i < 4; ++i)
        aoff[i] = (wr * 64 + i * 16 + lane16) * BK + slot;
#pragma unroll
    for (int j = 0; j < 4; ++j)
        boff[j] = (wc * 64 + j * 16 + lane16) * BK + slot;

    f32x4 acc[4][4] = {};

    // prologue: tile0 -> regs -> LDS buf0; tile1 -> regs
    LOADTILE(0);
    STORETILE(0);
    LOADTILE(1);
    lds_barrier();

#pragma unroll 2
    for (int it = 0; it < NITER - 2; ++it) {
        const int cur = it & 1, nxt = cur ^ 1;

        bf16x8 af[4], bfv[4];
#pragma unroll
        for (int i = 0; i < 4; ++i)
            af[i] = *(const bf16x8*)&As[cur][aoff[i]];
#pragma unroll
        for (int j = 0; j < 4; ++j)
            bfv[j] = *(const bf16x8*)&Bs[cur][boff[j]];
#pragma unroll
        for (int i = 0; i < 4; ++i)
#pragma unroll
            for (int j = 0; j < 4; ++j)
                acc[i][j] = __builtin_amdgcn_mfma_f32_16x16x32_bf16(
                    af[i], bfv[j], acc[i][j], 0, 0, 0);

        // stage tile it+1 (in regs since last iter) into buf[nxt]
        STORETILE(nxt);
        // issue loads for tile it+2 (ride across the lgkm-only barrier)
        LOADTILE(it + 2);
        lds_barrier();
    }

    // it = NITER-2: compute, stage last tile, no more loads
    {
        const int cur = (NITER - 2) & 1, nxt = cur ^ 1;
        bf16x8 af[4], bfv[4];
#pragma unroll
        for (int i = 0; i < 4; ++i)
            af[i] = *(const bf16x8*)&As[cur][aoff[i]];
#pragma unroll
        for (int j = 0; j < 4; ++j)
            bfv[j] = *(const bf16x8*)&Bs[cur][boff[j]];
#pragma unroll
        for (int i = 0; i < 4; ++i)
#pragma unroll
            for (int j = 0; j < 4; ++j)
                acc[i][j] = __builtin_amdgcn_mfma_f32_16x16x32_bf16(
                    af[i], bfv[j], acc[i][j], 0, 0, 0);
        STORETILE(nxt);
        lds_barrier();
    }

    // it = NITER-1: compute only
    {
        const int cur = (NITER - 1) & 1;
        bf16x8 af[4], bfv[4];
#pragma unroll
        for (int i = 0; i < 4; ++i)
            af[i] = *(const bf16x8*)&As[cur][aoff[i]];
#pragma unroll
        for (int j = 0; j < 4; ++j)
            bfv[j] = *(const bf16x8*)&Bs[cur][boff[j]];
#pragma unroll
        for (int i = 0; i < 4; ++i)
#pragma unroll
            for (int j = 0; j < 4; ++j)
                acc[i][j] = __builtin_amdgcn_mfma_f32_16x16x32_bf16(
                    af[i], bfv[j], acc[i][j], 0, 0, 0);
    }

    // epilogue: C[row][col] = acc + bias[col]  (unchanged, verified layout)
    float bv[4];
#pragma unroll
    for (int j = 0; j < 4; ++j)
        bv[j] = bias[colBase + wc * 64 + j * 16 + lane16];
#pragma unroll
    for (int i = 0; i < 4; ++i) {
        int row0 = rowBase + wr * 64 + i * 16 + quad * 4;
#pragma unroll
        for (int r = 0; r < 4; ++r) {
            float* cp = C + (size_t)(row0 + r) * N_DIM + colBase + wc * 64 + lane16;
#pragma unroll
            for (int j = 0; j < 4; ++j)
                cp[j * 16] = acc[i][j][r] + bv[j];
        }
    }
#undef LOADTILE
#undef STORETILE
}

extern "C" void kernel_launch(void* const* d_in, const int* in_sizes, int n_in,
                              void* d_out, int out_size, void* d_ws, size_t ws_size,
                              hipStream_t stream) {
    const float* x    = (const float*)d_in[0];
    const float* w    = (const float*)d_in[1];
    const float* bias = (const float*)d_in[2];
    float* out = (float*)d_out;
    (void)d_ws; (void)ws_size;

    hipLaunchKernelGGL(gemm_fused, dim3(N_DIM / BN, M_ROWS / BM), dim3(256),
                       0, stream, x, w, bias, out);
}

// Round 2
// 133.121 us; speedup vs baseline: 1.2086x; 1.2086x over previous
//
#include <hip/hip_runtime.h>
#include <stdint.h>

// Problem constants (fixed shapes from reference)
#define M_ROWS 6272   // 32*196
#define K_DIM  768
#define N_DIM  3072
#define BM 128
#define BN 256
#define BK 32
#define NITER (K_DIM / BK)   // 24

#define X_CHUNKS (M_ROWS * K_DIM / 8)   // 602112
#define W_CHUNKS (N_DIM * K_DIM / 8)    // 294912
#define X_BLOCKS (X_CHUNKS / 256)       // 2352
#define W_BLOCKS (W_CHUNKS / 256)       // 1152

#define GRID_X (N_DIM / BN)             // 12
#define GRID_Y (M_ROWS / BM)            // 49
#define NWG    (GRID_X * GRID_Y)        // 588

typedef unsigned short u16;
typedef __attribute__((ext_vector_type(8))) __bf16 bf16x8;
typedef __attribute__((ext_vector_type(4))) float f32x4;

__device__ __forceinline__ u16 f32_to_bf16(float f) {
    unsigned u = __float_as_uint(f);
    unsigned r = 0x7FFFu + ((u >> 16) & 1u);
    return (u16)((u + r) >> 16);
}

__device__ __forceinline__ unsigned pack2(float a, float b) {
    return (unsigned)f32_to_bf16(a) | ((unsigned)f32_to_bf16(b) << 16);
}

// LDS-only barrier: drains lgkmcnt (ds ops) but deliberately NOT vmcnt, so
// prefetched global loads stay in flight across the barrier. HIP's
// __syncthreads() always emits s_waitcnt vmcnt(0) before s_barrier, which
// welds global-load latency to every K-iteration.
__device__ __forceinline__ void lds_barrier() {
    asm volatile("s_waitcnt lgkmcnt(0)\n\ts_barrier" ::: "memory");
}

// Fused prep (verified round-0): blocks [0, X_BLOCKS) cast x fp32->bf16;
// blocks [X_BLOCKS, X_BLOCKS+W_BLOCKS) expand block-circulant W to bf16.
__global__ void prep_kernel(const float* __restrict__ x, const float* __restrict__ w,
                            u16* __restrict__ xb, u16* __restrict__ wb) {
    int b = blockIdx.x;
    if (b < X_BLOCKS) {
        int idx = b * 256 + threadIdx.x;
        const float4* xp = (const float4*)x + (size_t)idx * 2;
        float4 a = xp[0], c = xp[1];
        uint4 v;
        v.x = pack2(a.x, a.y);
        v.y = pack2(a.z, a.w);
        v.z = pack2(c.x, c.y);
        v.w = pack2(c.z, c.w);
        ((uint4*)xb)[idx] = v;
    } else {
        int idx = (b - X_BLOCKS) * 256 + threadIdx.x;
        int n    = idx / 96;          // output row [0,3072)
        int kc   = idx - n * 96;      // 8-elem chunk along K
        int kblk = n / 768;           // 0..3
        int o    = n - kblk * 768;    // 0..767
        int j    = kc / 24;           // 0..3
        int c8   = kc - j * 24;       // 0..23
        int i    = (kblk - j) & 3;    // (kblk - j) mod 4
        const float* src = w + (((size_t)i * 768 + o) * 192 + c8 * 8);
        float4 a = ((const float4*)src)[0];
        float4 c = ((const float4*)src)[1];
        uint4 v;
        v.x = pack2(a.x, a.y);
        v.y = pack2(a.z, a.w);
        v.z = pack2(c.x, c.y);
        v.w = pack2(c.z, c.w);
        ((uint4*)wb)[idx] = v;
    }
}

// C[m,n] = sum_k A[m,k]*B[n,k] + bias[n]; A,B bf16 row-major K-contig, C fp32.
//
// Geometry upgrade vs round-0: BM=128 x BN=256, 8 waves (2 row x 4 col),
// 512 threads. Per K-tile each thread stages 3 x 16B chunks (1 A + 2 B)
// instead of 4 -- staging bytes per FLOP drop 2.15x (B-panel reused by 2x
// more output columns). MFMA work per wave per barrier unchanged (16).
//
// Pipeline (verified round-0, unchanged): per iter each thread holds the
// NEXT tile's chunks in VGPRs (loaded one full iteration earlier), ds_writes
// them into the alternate LDS buffer after the MFMA phase, then issues loads
// for tile it+2. Barriers are lgkm-only so those loads ride across iterations.
//
// LDS XOR swizzle (verified, conflicts=0): 16B chunk for (row r, k-slot s)
// lives at slot s ^ ((r>>1)&3); applied on the GLOBAL source k-offset during
// staging, mirrored on the ds_read side.
//
// XCD-chunked block swizzle (bijective, m204 form): 588 blocks -> 8
// contiguous chunks of 73/74, so the 12 col-blocks sharing one A row-panel
// land on the same XCD's L2 instead of round-robining across all 8.
__global__ __launch_bounds__(512, 4) void gemm_bt(
    const u16* __restrict__ A,    // [M_ROWS, K_DIM] bf16
    const u16* __restrict__ B,    // [N_DIM,  K_DIM] bf16
    const float* __restrict__ bias,
    float* __restrict__ C)
{
    __shared__ __align__(16) u16 As[2][BM * BK];   // 2 x 8 KB
    __shared__ __align__(16) u16 Bs[2][BN * BK];   // 2 x 16 KB

    // ---- XCD-aware bijective remap of the 1-D block id ----
    const int orig = blockIdx.x;
    const int xcd  = orig & 7;
    const int pos  = orig >> 3;
    const int q    = NWG >> 3;          // 73
    const int r    = NWG & 7;           // 4
    const int lin  = (xcd < r ? xcd * (q + 1) : r * (q + 1) + (xcd - r) * q) + pos;
    const int rowBlk = lin / GRID_X;    // 0..48
    const int colBlk = lin - rowBlk * GRID_X;

    const int rowBase = rowBlk * BM;
    const int colBase = colBlk * BN;

    const int tid    = threadIdx.x;
    const int wave   = tid >> 6;
    const int lane   = tid & 63;
    const int lane16 = lane & 15;
    const int quad   = lane >> 4;
    const int wr     = wave >> 2;   // wave row (0..1) -> 64 rows each
    const int wc     = wave & 3;    // wave col (0..3) -> 64 cols each

    // staging: chunk c: row = c>>2, lds slot = c&3,
    // global k-slot = (c&3) ^ ((row>>1)&3). 16B per chunk.
    // A: 512 chunks -> 1/thread. B: 1024 chunks -> 2/thread.
    const int cA  = tid;
    const int rA  = cA >> 2,  sA  = (cA & 3) ^ ((rA >> 1) & 3);
    const int cB0 = tid;
    const int cB1 = tid + 512;
    const int rB0 = cB0 >> 2, sB0 = (cB0 & 3) ^ ((rB0 >> 1) & 3);
    const int rB1 = cB1 >> 2, sB1 = (cB1 & 3) ^ ((rB1 >> 1) & 3);

    const uint4* Ag  = (const uint4*)(A + (size_t)(rowBase + rA) * K_DIM + sA * 8);
    const uint4* Bg0 = (const uint4*)(B + (size_t)(colBase + rB0) * K_DIM + sB0 * 8);
    const uint4* Bg1 = (const uint4*)(B + (size_t)(colBase + rB1) * K_DIM + sB1 * 8);
    uint4* Al  = (uint4*)&As[0][cA * 8];
    uint4* Bl0 = (uint4*)&Bs[0][cB0 * 8];
    uint4* Bl1 = (uint4*)&Bs[0][cB1 * 8];
    const int aBufStride = (BM * BK) / 8;   // uint4 elements per A LDS buffer
    const int bBufStride = (BN * BK) / 8;   // uint4 elements per B LDS buffer

    // read-side swizzle
    const int swz  = (lane16 >> 1) & 3;
    const int slot = (quad ^ swz) * 8;
    int aoff[4], boff[4];
#pragma unroll
    for (int i = 0; i < 4; ++i)
        aoff[i] = (wr * 64 + i * 16 + lane16) * BK + slot;
#pragma unroll
    for (int j = 0; j < 4; ++j)
        boff[j] = (wc * 64 + j * 16 + lane16) * BK + slot;

    f32x4 acc[4][4] = {};

    // K-step in uint4 units
    const int kStep = BK / 8;   // 4

    // prologue: tile0 -> regs -> LDS buf0; tile1 -> regs
    uint4 ga = Ag[0], gb0 = Bg0[0], gb1 = Bg1[0];
    Al[0] = ga; Bl0[0] = gb0; Bl1[0] = gb1;
    ga = Ag[kStep]; gb0 = Bg0[kStep]; gb1 = Bg1[kStep];
    lds_barrier();

#pragma unroll 2
    for (int it = 0; it < NITER - 2; ++it) {
        const int cur = it & 1, nxt = cur ^ 1;

        bf16x8 af[4], bfv[4];
#pragma unroll
        for (int i = 0; i < 4; ++i)
            af[i] = *(const bf16x8*)&As[cur][aoff[i]];
#pragma unroll
        for (int j = 0; j < 4; ++j)
            bfv[j] = *(const bf16x8*)&Bs[cur][boff[j]];
#pragma unroll
        for (int i = 0; i < 4; ++i)
#pragma unroll
            for (int j = 0; j < 4; ++j)
                acc[i][j] = __builtin_amdgcn_mfma_f32_16x16x32_bf16(
                    af[i], bfv[j], acc[i][j], 0, 0, 0);

        // stage tile it+1 (already in regs) into buf[nxt]
        Al[nxt * aBufStride]  = ga;
        Bl0[nxt * bBufStride] = gb0;
        Bl1[nxt * bBufStride] = gb1;
        // issue loads for tile it+2
        const int g = (it + 2) * kStep;
        ga = Ag[g]; gb0 = Bg0[g]; gb1 = Bg1[g];
        lds_barrier();
    }

    // it = NITER-2: compute, stage last tile, no more loads
    {
        const int cur = (NITER - 2) & 1, nxt = cur ^ 1;
        bf16x8 af[4], bfv[4];
#pragma unroll
        for (int i = 0; i < 4; ++i)
            af[i] = *(const bf16x8*)&As[cur][aoff[i]];
#pragma unroll
        for (int j = 0; j < 4; ++j)
            bfv[j] = *(const bf16x8*)&Bs[cur][boff[j]];
#pragma unroll
        for (int i = 0; i < 4; ++i)
#pragma unroll
            for (int j = 0; j < 4; ++j)
                acc[i][j] = __builtin_amdgcn_mfma_f32_16x16x32_bf16(
                    af[i], bfv[j], acc[i][j], 0, 0, 0);
        Al[nxt * aBufStride]  = ga;
        Bl0[nxt * bBufStride] = gb0;
        Bl1[nxt * bBufStride] = gb1;
        lds_barrier();
    }

    // it = NITER-1: compute only
    {
        const int cur = (NITER - 1) & 1;
        bf16x8 af[4], bfv[4];
#pragma unroll
        for (int i = 0; i < 4; ++i)
            af[i] = *(const bf16x8*)&As[cur][aoff[i]];
#pragma unroll
        for (int j = 0; j < 4; ++j)
            bfv[j] = *(const bf16x8*)&Bs[cur][boff[j]];
#pragma unroll
        for (int i = 0; i < 4; ++i)
#pragma unroll
            for (int j = 0; j < 4; ++j)
                acc[i][j] = __builtin_amdgcn_mfma_f32_16x16x32_bf16(
                    af[i], bfv[j], acc[i][j], 0, 0, 0);
    }

    // epilogue: C[row][col] = acc + bias[col]  (verified layout)
    float bv[4];
#pragma unroll
    for (int j = 0; j < 4; ++j)
        bv[j] = bias[colBase + wc * 64 + j * 16 + lane16];
#pragma unroll
    for (int i = 0; i < 4; ++i) {
        int row0 = rowBase + wr * 64 + i * 16 + quad * 4;
#pragma unroll
        for (int r2 = 0; r2 < 4; ++r2) {
            float* cp = C + (size_t)(row0 + r2) * N_DIM + colBase + wc * 64 + lane16;
#pragma unroll
            for (int j = 0; j < 4; ++j)
                cp[j * 16] = acc[i][j][r2] + bv[j];
        }
    }
}

extern "C" void kernel_launch(void* const* d_in, const int* in_sizes, int n_in,
                              void* d_out, int out_size, void* d_ws, size_t ws_size,
                              hipStream_t stream) {
    const float* x    = (const float*)d_in[0];
    const float* w    = (const float*)d_in[1];
    const float* bias = (const float*)d_in[2];
    float* out = (float*)d_out;

    u16* xb = (u16*)d_ws;                                       // 9,633,792 B
    u16* wb = (u16*)((char*)d_ws + (size_t)M_ROWS * K_DIM * 2); // +4,718,592 B

    hipLaunchKernelGGL(prep_kernel, dim3(X_BLOCKS + W_BLOCKS), dim3(256),
                       0, stream, x, w, xb, wb);
    hipLaunchKernelGGL(gemm_bt, dim3(NWG), dim3(512),
                       0, stream, xb, wb, bias, out);
}